// Round 4
// baseline (313.814 us; speedup 1.0000x reference)
//
#include <hip/hip_runtime.h>

// FP8 E4M3 bit-level multiplier — persistent grid-stride loop.
// Session history: one-shot-wave versions plateau at ~103 us (3.9 TB/s CU-side
// vs 6.3 TB/s copy ceiling). Theory: each short-lived wave pays one full
// queued memory latency per 3KB moved + wg launch churn. Fix: copy-bench
// shape — 2048 persistent blocks, grid-stride loop, 1-deep register prefetch
// so every wave keeps 2 loads in flight while computing/storing.
// Exchange via __shfl_xor (LDS pipe, known-good from the 103us baseline;
// DPP variant was bundled in regressed rounds). Plain cached stores
// (nontemporal cost +13us in round 2). Bit-23 nibble compaction.

#define BIAS 7

typedef float vfloat4 __attribute__((ext_vector_type(4)));

__device__ __forceinline__ int rne_rshift(int M, int sh) {
    // round-to-nearest-even right shift of non-negative M by sh >= 0
    int q = M >> sh;
    int rem = M - (q << sh);
    int half = (1 << sh) >> 1;           // 2^(sh-1), 0 when sh==0
    int up = ((rem > half) | ((rem == half) & (q & 1))) & (sh > 0);
    return q + up;
}

__device__ __forceinline__ int fp8_mul_byte(int a8, int b8) {
    int sa = a8 >> 7,        sb_ = b8 >> 7;
    int ea = (a8 >> 3) & 15, eb = (b8 >> 3) & 15;
    int ma = a8 & 7,         mb = b8 & 7;

    int sig_a = (ea == 0) ? ma : (ma + 8);
    int sig_b = (eb == 0) ? mb : (mb + 8);
    int exa = ((ea == 0) ? 1 : ea) - BIAS;
    int exb = ((eb == 0) ? 1 : eb) - BIAS;

    int M = sig_a * sig_b;              // exact product, <= 225
    int E = exa + exb - 6;              // value = M * 2^E

    int p = (M > 0) ? (31 - __clz(M)) : 0;
    int eb_out = E + p + BIAS;

    // normal path (eb_out >= 1): RNE round to 3 mantissa bits
    int sh  = p - 3;
    int shp = (sh > 0) ? sh : 0;
    int lsh = (sh < 0) ? -sh : 0;
    int mant4 = rne_rshift(M, shp) << lsh;   // in [8, 16]
    int carry = mant4 >> 4;
    if (mant4 == 16) mant4 = 8;
    int e_n = eb_out + carry;
    int m_n = mant4 - 8;
    if (e_n >= 16) { e_n = 15; m_n = 7; }    // overflow -> NaN

    // subnormal path (eb_out <= 0): mant = RNE(M * 2^(E+9))
    int t = E + 9;
    int rsh   = (-t < 0) ? 0 : ((-t > 30) ? 30 : -t);
    int lsh_s = (t > 0) ? t : 0;
    int mant_s = rne_rshift(M, rsh) << lsh_s;
    int e_s = (mant_s >= 8) ? 1 : 0;
    int m_s = (mant_s >= 8) ? 0 : mant_s;

    int is_sub = (eb_out <= 0);
    int e_o = is_sub ? e_s : e_n;
    int m_o = is_sub ? m_s : m_n;
    if (M == 0) { e_o = 0; m_o = 0; }
    int s_o = sa ^ sb_;
    return (s_o << 7) | (e_o << 3) | m_o;
}

// inputs are exactly 0.0f (0x00000000) or 1.0f (0x3F800000): bit 23 is the bit.
// packs a-nibble into bits 3..0, b-nibble into bits 7..4.
__device__ __forceinline__ int compact_own(uint4 av, uint4 bv) {
    return (int)(((av.x >> 20) & 8u)   | ((av.y >> 21) & 4u)  |
                 ((av.z >> 22) & 2u)   | ((av.w >> 23) & 1u)  |
                 ((bv.x >> 16) & 128u) | ((bv.y >> 17) & 64u) |
                 ((bv.z >> 18) & 32u)  | ((bv.w >> 19) & 16u));
}

__device__ __forceinline__ void compute_store(uint4 av, uint4 bv, int odd, int sbit,
                                              vfloat4* __restrict__ dst) {
    int own = compact_own(av, bv);
    int pp  = __shfl_xor(own, 1);        // partner lane's nibbles (LDS pipe)

    // even lane holds [s,e3,e2,e1] (high nibble of code), odd holds [e0,m2,m1,m0]
    int a8 = odd ? (((pp  & 0xF) << 4)        |  (own & 0xF))
                 : (((own & 0xF) << 4)        |  (pp  & 0xF));
    int b8 = odd ? ((((pp  >> 4) & 0xF) << 4) | ((own >> 4) & 0xF))
                 : ((((own >> 4) & 0xF) << 4) | ((pp  >> 4) & 0xF));

    int r = fp8_mul_byte(a8, b8);

    vfloat4 o;
    o.x = (float)((r >> sbit)       & 1);
    o.y = (float)((r >> (sbit - 1)) & 1);
    o.z = (float)((r >> (sbit - 2)) & 1);
    o.w = (float)((r >> (sbit - 3)) & 1);
    *dst = o;                             // plain cached store
}

__global__ void __launch_bounds__(256)
fp8_mul_kernel(const uint4* __restrict__ a, const uint4* __restrict__ b,
               vfloat4* __restrict__ out, int n_vec, int stride) {
    int j = blockIdx.x * blockDim.x + threadIdx.x;
    if (j >= n_vec) return;

    const int odd  = threadIdx.x & 1;     // stride is even -> parity of j invariant
    const int sbit = odd ? 3 : 7;         // which 4 result bits this lane stores

    uint4 av = a[j];
    uint4 bv = b[j];

    for (;;) {
        // prefetch next iteration (1-deep): keeps 2 loads in flight under
        // the compute+store of the current element.
        int jn = j + stride;
        bool more = (jn < n_vec);         // uniform across lane pairs (n_vec even)
        uint4 av_n, bv_n;
        if (more) { av_n = a[jn]; bv_n = b[jn]; }

        compute_store(av, bv, odd, sbit, &out[j]);

        if (!more) break;
        av = av_n; bv = bv_n; j = jn;
    }
}

extern "C" void kernel_launch(void* const* d_in, const int* in_sizes, int n_in,
                              void* d_out, int out_size, void* d_ws, size_t ws_size,
                              hipStream_t stream) {
    const uint4* a = (const uint4*)d_in[0];
    const uint4* b = (const uint4*)d_in[1];
    vfloat4* out = (vfloat4*)d_out;
    int n_vec = in_sizes[0] / 4;          // one float4 (half group) per thread-slot
    int block = 256;
    int grid_needed = (n_vec + block - 1) / block;
    int grid = grid_needed < 2048 ? grid_needed : 2048;   // 8 wg/CU -> 32 waves/CU
    int stride = grid * block;
    fp8_mul_kernel<<<grid, block, 0, stream>>>(a, b, out, n_vec, stride);
}

// Round 5
// 302.043 us; speedup vs baseline: 1.0390x; 1.0390x over previous
//
#include <hip/hip_runtime.h>

// FP8 E4M3 bit-level multiplier — one thread per full bit-group.
// Session scoreboard: one-shot KPT=1 + shfl = 103us; KPT=4 batch = 113;
// persistent+prefetch = 115; nt stores = 126. The one-shot shape wins.
// This round keeps that shape but gives each thread the WHOLE 8-bit group
// (2 consecutive float4s per input): no __shfl_xor in the dependent chain
// (no lgkmcnt wait), and no redundant duplicate product per lane pair
// (per-group VALU ~150 -> ~95 ops). Loads: 2x uint4 per input, 32B
// contiguous per lane; wave's two loads hit the same cache lines -> no
// extra DRAM traffic. Plain cached stores (nt regressed in R2).

#define BIAS 7

typedef float vfloat4 __attribute__((ext_vector_type(4)));

__device__ __forceinline__ int rne_rshift(int M, int sh) {
    // round-to-nearest-even right shift of non-negative M by sh >= 0
    int q = M >> sh;
    int rem = M - (q << sh);
    int half = (1 << sh) >> 1;           // 2^(sh-1), 0 when sh==0
    int up = ((rem > half) | ((rem == half) & (q & 1))) & (sh > 0);
    return q + up;
}

__device__ __forceinline__ int fp8_mul_byte(int a8, int b8) {
    int sa = a8 >> 7,        sb_ = b8 >> 7;
    int ea = (a8 >> 3) & 15, eb = (b8 >> 3) & 15;
    int ma = a8 & 7,         mb = b8 & 7;

    int sig_a = (ea == 0) ? ma : (ma + 8);
    int sig_b = (eb == 0) ? mb : (mb + 8);
    int exa = ((ea == 0) ? 1 : ea) - BIAS;
    int exb = ((eb == 0) ? 1 : eb) - BIAS;

    int M = sig_a * sig_b;              // exact product, <= 225
    int E = exa + exb - 6;              // value = M * 2^E

    int p = (M > 0) ? (31 - __clz(M)) : 0;
    int eb_out = E + p + BIAS;

    // normal path (eb_out >= 1): RNE round to 3 mantissa bits
    int sh  = p - 3;
    int shp = (sh > 0) ? sh : 0;
    int lsh = (sh < 0) ? -sh : 0;
    int mant4 = rne_rshift(M, shp) << lsh;   // in [8, 16]
    int carry = mant4 >> 4;
    if (mant4 == 16) mant4 = 8;
    int e_n = eb_out + carry;
    int m_n = mant4 - 8;
    if (e_n >= 16) { e_n = 15; m_n = 7; }    // overflow -> NaN

    // subnormal path (eb_out <= 0): mant = RNE(M * 2^(E+9))
    int t = E + 9;
    int rsh   = (-t < 0) ? 0 : ((-t > 30) ? 30 : -t);
    int lsh_s = (t > 0) ? t : 0;
    int mant_s = rne_rshift(M, rsh) << lsh_s;
    int e_s = (mant_s >= 8) ? 1 : 0;
    int m_s = (mant_s >= 8) ? 0 : mant_s;

    int is_sub = (eb_out <= 0);
    int e_o = is_sub ? e_s : e_n;
    int m_o = is_sub ? m_s : m_n;
    if (M == 0) { e_o = 0; m_o = 0; }
    int s_o = sa ^ sb_;
    return (s_o << 7) | (e_o << 3) | m_o;
}

// inputs are exactly 0.0f (0x00000000) or 1.0f (0x3F800000): bit 23 is the bit.
// v0 = {bit7,bit6,bit5,bit4} = [s,e3,e2,e1], v1 = {bit3,bit2,bit1,bit0} = [e0,m2,m1,m0]
__device__ __forceinline__ int compact8(uint4 v0, uint4 v1) {
    return (int)(((v0.x >> 16) & 128u) | ((v0.y >> 17) & 64u) |
                 ((v0.z >> 18) & 32u)  | ((v0.w >> 19) & 16u) |
                 ((v1.x >> 20) & 8u)   | ((v1.y >> 21) & 4u)  |
                 ((v1.z >> 22) & 2u)   | ((v1.w >> 23) & 1u));
}

__global__ void __launch_bounds__(256)
fp8_mul_kernel(const uint4* __restrict__ a, const uint4* __restrict__ b,
               vfloat4* __restrict__ out, int n_grp) {
    int g = blockIdx.x * blockDim.x + threadIdx.x;
    if (g >= n_grp) return;

    uint4 a0 = a[2 * g], a1 = a[2 * g + 1];
    uint4 b0 = b[2 * g], b1 = b[2 * g + 1];

    int a8 = compact8(a0, a1);
    int b8 = compact8(b0, b1);
    int r  = fp8_mul_byte(a8, b8);

    vfloat4 o0, o1;
    o0.x = (float)((r >> 7) & 1);   // s
    o0.y = (float)((r >> 6) & 1);   // e3
    o0.z = (float)((r >> 5) & 1);   // e2
    o0.w = (float)((r >> 4) & 1);   // e1
    o1.x = (float)((r >> 3) & 1);   // e0
    o1.y = (float)((r >> 2) & 1);   // m2
    o1.z = (float)((r >> 1) & 1);   // m1
    o1.w = (float)( r       & 1);   // m0
    out[2 * g]     = o0;
    out[2 * g + 1] = o1;
}

extern "C" void kernel_launch(void* const* d_in, const int* in_sizes, int n_in,
                              void* d_out, int out_size, void* d_ws, size_t ws_size,
                              hipStream_t stream) {
    const uint4* a = (const uint4*)d_in[0];
    const uint4* b = (const uint4*)d_in[1];
    vfloat4* out = (vfloat4*)d_out;
    int n_grp = in_sizes[0] / 8;          // one full bit-group (2 float4s) per thread
    int block = 256;
    int grid = (n_grp + block - 1) / block;
    fp8_mul_kernel<<<grid, block, 0, stream>>>(a, b, out, n_grp);
}